// Round 1
// baseline (430.047 us; speedup 1.0000x reference)
//
#include <hip/hip_runtime.h>
#include <hip/hip_cooperative_groups.h>

namespace cg = cooperative_groups;

// ---------------------------------------------------------------------------
// FP8Linear: out = (q8(x*sx) @ q8(W*sw)^T) / (sx*sw) + bias
// M=16384, K=2048, N=2048
// R3: side passes fused into ONE cooperative kernel (partial amax ->
// grid.sync -> quantize), no memset / no atomics / partials live in d_out.
// GEMM: + XCD-aware bijective block swizzle (B becomes L2-resident per XCD),
// + nontemporal C stores (keep fp8 operands and x in L2/LLC).
// ---------------------------------------------------------------------------

typedef __attribute__((ext_vector_type(4))) float floatx4;
typedef __attribute__((ext_vector_type(4))) int intx4;
typedef __attribute__((ext_vector_type(8))) int intx8;

#define FP8_MAX_F 448.0f
#define SIDE_GRID 1024

__device__ __forceinline__ void async_load16(const void* g, void* l) {
    __builtin_amdgcn_global_load_lds(
        (const __attribute__((address_space(1))) unsigned int*)g,
        (__attribute__((address_space(3))) unsigned int*)l,
        16, 0, 0);
}

__device__ __forceinline__ float scale_from_amax_f(float a) {
    // must be the exact fp32 op sequence everywhere it is recomputed
    return FP8_MAX_F / (a + 1e-12f) * 0.9f;
}
__device__ __forceinline__ float scale_from_amax(unsigned int bits) {
    return scale_from_amax_f(__uint_as_float(bits));
}

// --- fused: partial amax (x and w) -> grid sync -> global reduce -> quantize.
// partials[] lives in the output buffer (gemm overwrites it afterwards).
__global__ __launch_bounds__(256) void amax_quant(
    const float* __restrict__ x, long xn4,
    const float* __restrict__ w, long wn4,
    float* __restrict__ partials,        // [2*SIDE_GRID] (in d_out)
    unsigned int* __restrict__ amax,     // 2 u32 in ws (for gemm epilogue)
    unsigned int* __restrict__ xq,
    unsigned int* __restrict__ wq) {
    const float4* xv = (const float4*)x;
    const float4* wv = (const float4*)w;
    const long tid = (long)blockIdx.x * 256 + threadIdx.x;
    const long stride = (long)SIDE_GRID * 256;
    const int lane = threadIdx.x & 63, wid = threadIdx.x >> 6;
    __shared__ float red[2][4];

    // phase 1: per-block partial max over both tensors (balanced split)
    float mx = 0.0f, mw = 0.0f;
    for (long j = tid; j < xn4; j += stride) {
        float4 v = xv[j];
        mx = fmaxf(mx, fmaxf(fmaxf(fabsf(v.x), fabsf(v.y)),
                             fmaxf(fabsf(v.z), fabsf(v.w))));
    }
    for (long j = tid; j < wn4; j += stride) {
        float4 v = wv[j];
        mw = fmaxf(mw, fmaxf(fmaxf(fabsf(v.x), fabsf(v.y)),
                             fmaxf(fabsf(v.z), fabsf(v.w))));
    }
    #pragma unroll
    for (int off = 32; off > 0; off >>= 1) {
        mx = fmaxf(mx, __shfl_down(mx, off));
        mw = fmaxf(mw, __shfl_down(mw, off));
    }
    if (lane == 0) { red[0][wid] = mx; red[1][wid] = mw; }
    __syncthreads();
    if (threadIdx.x == 0) {
        partials[blockIdx.x] =
            fmaxf(fmaxf(red[0][0], red[0][1]), fmaxf(red[0][2], red[0][3]));
        partials[SIDE_GRID + blockIdx.x] =
            fmaxf(fmaxf(red[1][0], red[1][1]), fmaxf(red[1][2], red[1][3]));
    }

    cg::this_grid().sync();

    // phase 2: redundant per-block global reduce (deterministic, identical
    // result in every block and identical to what gemm recomputes from bits)
    mx = 0.0f; mw = 0.0f;
    for (int p = threadIdx.x; p < SIDE_GRID; p += 256) {
        mx = fmaxf(mx, partials[p]);
        mw = fmaxf(mw, partials[SIDE_GRID + p]);
    }
    #pragma unroll
    for (int off = 32; off > 0; off >>= 1) {
        mx = fmaxf(mx, __shfl_down(mx, off));
        mw = fmaxf(mw, __shfl_down(mw, off));
    }
    if (lane == 0) { red[0][wid] = mx; red[1][wid] = mw; }
    __syncthreads();
    mx = fmaxf(fmaxf(red[0][0], red[0][1]), fmaxf(red[0][2], red[0][3]));
    mw = fmaxf(fmaxf(red[1][0], red[1][1]), fmaxf(red[1][2], red[1][3]));
    if (blockIdx.x == 0 && threadIdx.x == 0) {
        amax[0] = __float_as_uint(mx);
        amax[1] = __float_as_uint(mw);
    }

    // phase 3: quantize (second read hits LLC; C was stored nontemporally)
    const float sx = scale_from_amax_f(mx);
    const float sw = scale_from_amax_f(mw);
    for (long j = tid; j < xn4; j += stride) {
        float4 v = xv[j];
        float a0 = fminf(fmaxf(v.x * sx, -FP8_MAX_F), FP8_MAX_F);
        float a1 = fminf(fmaxf(v.y * sx, -FP8_MAX_F), FP8_MAX_F);
        float a2 = fminf(fmaxf(v.z * sx, -FP8_MAX_F), FP8_MAX_F);
        float a3 = fminf(fmaxf(v.w * sx, -FP8_MAX_F), FP8_MAX_F);
        int p = __builtin_amdgcn_cvt_pk_fp8_f32(a0, a1, 0, false);
        p = __builtin_amdgcn_cvt_pk_fp8_f32(a2, a3, p, true);
        xq[j] = (unsigned int)p;
    }
    for (long j = tid; j < wn4; j += stride) {
        float4 v = wv[j];
        float a0 = fminf(fmaxf(v.x * sw, -FP8_MAX_F), FP8_MAX_F);
        float a1 = fminf(fmaxf(v.y * sw, -FP8_MAX_F), FP8_MAX_F);
        float a2 = fminf(fmaxf(v.z * sw, -FP8_MAX_F), FP8_MAX_F);
        float a3 = fminf(fmaxf(v.w * sw, -FP8_MAX_F), FP8_MAX_F);
        int p = __builtin_amdgcn_cvt_pk_fp8_f32(a0, a1, 0, false);
        p = __builtin_amdgcn_cvt_pk_fp8_f32(a2, a3, p, true);
        wq[j] = (unsigned int)p;
    }
}

// --- GEMM: C[m,n] = sum_k A8[m,k]*W8[n,k]; epilogue C = acc*rcp + bias[n]
// 128x128 tile, BK=128 bytes, 4 waves x 4x4 tiles of 16x16x128 scaled-fp8 MFMA.
// LDS layout XOR-swizzled at 16B granularity: LDS[r][b] = G[r][b ^ (r&7)].
#define BM 128
#define BN 128
#define BKB 128

__global__ __launch_bounds__(256, 3) void gemm_fp8mx(
    const unsigned char* __restrict__ A,  // [M,K] fp8
    const unsigned char* __restrict__ B,  // [N,K] fp8
    const float* __restrict__ bias,       // [N]
    const unsigned int* __restrict__ amax,
    float* __restrict__ C,                // [M,N] fp32
    int M, int N, int K) {
    __shared__ __align__(16) unsigned char As[BM * BKB];  // 16 KB
    __shared__ __align__(16) unsigned char Bs[BN * BKB];  // 16 KB

    const int t = threadIdx.x;
    const int lane = t & 63;
    const int w = t >> 6;

    // XCD-aware bijective swizzle: XCD k (flat%8==k) computes 256 consecutive
    // tiles = 16 full A-panel rows x all 16 B columns -> B (4MB) L2-resident.
    int flat = blockIdx.y * gridDim.x + blockIdx.x;
    const int nwg = gridDim.x * gridDim.y;
    if ((nwg & 7) == 0) flat = (flat & 7) * (nwg >> 3) + (flat >> 3);
    const int bm = (flat / gridDim.x) * BM;
    const int bn = (flat % gridDim.x) * BN;

    const int wm = (w >> 1) * 64;
    const int wn = (w & 1) * 64;

    floatx4 acc[4][4] = {};

    // staging: thread t -> LDS linear slot t*16 == (row = t>>3, blk = t&7);
    // load the XOR-swizzled global 16B block so LDS[r][b] = G[r][b^(r&7)]
    const int srow = t >> 3;                       // 0..31
    const int gcol = ((t & 7) ^ (srow & 7)) * 16;  // swizzled 16B block
    const unsigned char* gA = A + (long)(bm + srow) * K + gcol;
    const unsigned char* gB = B + (long)(bn + srow) * K + gcol;
    unsigned char* lA = As + t * 16;
    unsigned char* lB = Bs + t * 16;

    // fragment addressing: 16x16x128 f8f6f4 A/B: lane holds
    // elem (l&15, (l>>4)*32 + j), j=0..31 -> two swizzled 16B reads
    const int fr = lane & 15;
    const int sw = fr & 7;
    const int b0 = (lane >> 4) * 2;
    const int off0 = (b0 ^ sw) * 16;
    const int off1 = ((b0 + 1) ^ sw) * 16;
    const int rowA = (wm + fr) * BKB;
    const int rowB = (wn + fr) * BKB;

    for (int kt = 0; kt < K; kt += BKB) {
        __syncthreads();
        #pragma unroll
        for (int c = 0; c < 4; c++) {
            async_load16(gA + (long)c * 32 * K + kt, lA + c * 4096);
            async_load16(gB + (long)c * 32 * K + kt, lB + c * 4096);
        }
        __syncthreads();

        intx8 bfrag[4];
        #pragma unroll
        for (int j = 0; j < 4; j++) {
            intx4 lo = *(const intx4*)(Bs + rowB + j * 2048 + off0);
            intx4 hi = *(const intx4*)(Bs + rowB + j * 2048 + off1);
            bfrag[j] = (intx8){lo.x, lo.y, lo.z, lo.w, hi.x, hi.y, hi.z, hi.w};
        }
        #pragma unroll
        for (int i = 0; i < 4; i++) {
            intx4 lo = *(const intx4*)(As + rowA + i * 2048 + off0);
            intx4 hi = *(const intx4*)(As + rowA + i * 2048 + off1);
            intx8 afrag = (intx8){lo.x, lo.y, lo.z, lo.w, hi.x, hi.y, hi.z, hi.w};
            #pragma unroll
            for (int j = 0; j < 4; j++)
                acc[i][j] = __builtin_amdgcn_mfma_scale_f32_16x16x128_f8f6f4(
                    afrag, bfrag[j], acc[i][j],
                    /*cbsz=fp8*/ 0, /*blgp=fp8*/ 0,
                    0, 0x7f7f7f7f, 0, 0x7f7f7f7f);  // unit e8m0 scales
        }
    }

    // epilogue: C/D layout col = lane&15, row = (lane>>4)*4 + reg (16x16 shapes)
    const float is = scale_from_amax(amax[0]);
    const float ws = scale_from_amax(amax[1]);
    const float rcp = 1.0f / (is * ws);
    const int crow = bm + wm + (lane >> 4) * 4;
    const int ccol = bn + wn + fr;
    #pragma unroll
    for (int j = 0; j < 4; j++) {
        const int col = ccol + j * 16;
        const float bv = bias[col];
        #pragma unroll
        for (int i = 0; i < 4; i++) {
            const int row0 = crow + i * 16;
            #pragma unroll
            for (int r = 0; r < 4; r++)
                __builtin_nontemporal_store(acc[i][j][r] * rcp + bv,
                                            &C[(long)(row0 + r) * N + col]);
        }
    }
}

extern "C" void kernel_launch(void* const* d_in, const int* in_sizes, int n_in,
                              void* d_out, int out_size, void* d_ws, size_t ws_size,
                              hipStream_t stream) {
    const float* x = (const float*)d_in[0];    // [B,S,K] fp32
    const float* wt = (const float*)d_in[1];   // [N,K] fp32
    const float* bias = (const float*)d_in[2]; // [N] fp32
    float* out = (float*)d_out;                // [B*S, N] fp32

    const int xn = in_sizes[0];  // M*K
    const int wn = in_sizes[1];  // N*K
    const int N = in_sizes[2];
    const int K = wn / N;
    const int M = xn / K;

    unsigned char* wsb = (unsigned char*)d_ws;
    unsigned int* amax = (unsigned int*)wsb;   // 2 u32
    unsigned char* xq = wsb + 64;              // M*K bytes
    unsigned char* wq = wsb + 64 + (size_t)xn; // N*K bytes

    // partials parked in the output buffer (gemm overwrites all of it later)
    float* partials = out;
    long xn4 = (long)xn / 4, wn4 = (long)wn / 4;
    const float* xa = x;
    const float* wa = wt;
    unsigned int* xqa = (unsigned int*)xq;
    unsigned int* wqa = (unsigned int*)wq;
    void* kargs[] = {(void*)&xa, (void*)&xn4, (void*)&wa, (void*)&wn4,
                     (void*)&partials, (void*)&amax, (void*)&xqa, (void*)&wqa};
    hipLaunchCooperativeKernel((void*)amax_quant, dim3(SIDE_GRID), dim3(256),
                               kargs, 0, stream);

    dim3 grid(N / BN, M / BM);
    gemm_fp8mx<<<grid, 256, 0, stream>>>(xq, wq, bias, amax, out, M, N, K);
}

// Round 2
// 356.285 us; speedup vs baseline: 1.2070x; 1.2070x over previous
//
#include <hip/hip_runtime.h>

// ---------------------------------------------------------------------------
// FP8Linear: out = (q8(x*sx) @ q8(W*sw)^T) / (sx*sw) + bias
// M=16384, K=2048, N=2048
// R4: no cooperative sync (R1 regression: device-scope grid barrier + coop
// launch overhead). Side chain = 2 dispatches, no memset, no atomics:
//   amax_partial: per-block max -> partials[2][2048] in ws (plain stores)
//   quant_both:   every block redundantly reduces partials (16KB, L2-hot),
//                 writes amax bits for gemm, quantizes x and w
// GEMM: XCD-aware bijective swizzle kept; NT stores REVERTED (suspect in R1).
// ---------------------------------------------------------------------------

typedef __attribute__((ext_vector_type(4))) float floatx4;
typedef __attribute__((ext_vector_type(4))) int intx4;
typedef __attribute__((ext_vector_type(8))) int intx8;

#define FP8_MAX_F 448.0f
#define SGRID 2048

__device__ __forceinline__ void async_load16(const void* g, void* l) {
    __builtin_amdgcn_global_load_lds(
        (const __attribute__((address_space(1))) unsigned int*)g,
        (__attribute__((address_space(3))) unsigned int*)l,
        16, 0, 0);
}

__device__ __forceinline__ float scale_from_amax_f(float a) {
    // must be the exact fp32 op sequence everywhere it is recomputed
    return FP8_MAX_F / (a + 1e-12f) * 0.9f;
}
__device__ __forceinline__ float scale_from_amax(unsigned int bits) {
    return scale_from_amax_f(__uint_as_float(bits));
}

// --- pass 1: per-block partial amax over x and w (balanced, all blocks do
// both). Plain stores to partials -> no memset, no atomics.
__global__ __launch_bounds__(256) void amax_partial(
    const float* __restrict__ x, long xn4,
    const float* __restrict__ w, long wn4,
    float* __restrict__ partials) {  // [2][SGRID] in ws
    const float4* xv = (const float4*)x;
    const float4* wv = (const float4*)w;
    const long tid = (long)blockIdx.x * 256 + threadIdx.x;
    const long stride = (long)SGRID * 256;

    float mx = 0.0f, mw = 0.0f;
    #pragma unroll 4
    for (long j = tid; j < xn4; j += stride) {
        float4 v = xv[j];
        mx = fmaxf(mx, fmaxf(fmaxf(fabsf(v.x), fabsf(v.y)),
                             fmaxf(fabsf(v.z), fabsf(v.w))));
    }
    #pragma unroll 2
    for (long j = tid; j < wn4; j += stride) {
        float4 v = wv[j];
        mw = fmaxf(mw, fmaxf(fmaxf(fabsf(v.x), fabsf(v.y)),
                             fmaxf(fabsf(v.z), fabsf(v.w))));
    }
    #pragma unroll
    for (int off = 32; off > 0; off >>= 1) {
        mx = fmaxf(mx, __shfl_down(mx, off));
        mw = fmaxf(mw, __shfl_down(mw, off));
    }
    __shared__ float red[2][4];
    const int lane = threadIdx.x & 63, wid = threadIdx.x >> 6;
    if (lane == 0) { red[0][wid] = mx; red[1][wid] = mw; }
    __syncthreads();
    if (threadIdx.x == 0) {
        partials[blockIdx.x] =
            fmaxf(fmaxf(red[0][0], red[0][1]), fmaxf(red[0][2], red[0][3]));
        partials[SGRID + blockIdx.x] =
            fmaxf(fmaxf(red[1][0], red[1][1]), fmaxf(red[1][2], red[1][3]));
    }
}

// --- pass 2: redundant partials reduce (every block, deterministic) ->
// write amax bits (block 0) -> quantize x and w. x/w re-reads hit LLC.
__global__ __launch_bounds__(256) void quant_both(
    const float* __restrict__ x, long xn4,
    const float* __restrict__ w, long wn4,
    const float* __restrict__ partials,
    unsigned int* __restrict__ amax,    // 2 u32 for gemm epilogue
    unsigned int* __restrict__ xq,
    unsigned int* __restrict__ wq) {
    // reduce 2*SGRID partials redundantly in every block
    float mx = 0.0f, mw = 0.0f;
    for (int p = threadIdx.x; p < SGRID; p += 256) {
        mx = fmaxf(mx, partials[p]);
        mw = fmaxf(mw, partials[SGRID + p]);
    }
    #pragma unroll
    for (int off = 32; off > 0; off >>= 1) {
        mx = fmaxf(mx, __shfl_down(mx, off));
        mw = fmaxf(mw, __shfl_down(mw, off));
    }
    __shared__ float red[2][4];
    const int lane = threadIdx.x & 63, wid = threadIdx.x >> 6;
    if (lane == 0) { red[0][wid] = mx; red[1][wid] = mw; }
    __syncthreads();
    mx = fmaxf(fmaxf(red[0][0], red[0][1]), fmaxf(red[0][2], red[0][3]));
    mw = fmaxf(fmaxf(red[1][0], red[1][1]), fmaxf(red[1][2], red[1][3]));
    if (blockIdx.x == 0 && threadIdx.x == 0) {
        amax[0] = __float_as_uint(mx);
        amax[1] = __float_as_uint(mw);
    }

    const float sx = scale_from_amax_f(mx);
    const float sw = scale_from_amax_f(mw);
    const float4* xv = (const float4*)x;
    const float4* wv = (const float4*)w;
    const long tid = (long)blockIdx.x * 256 + threadIdx.x;
    const long stride = (long)SGRID * 256;
    #pragma unroll 2
    for (long j = tid; j < xn4; j += stride) {
        float4 v = xv[j];
        float a0 = fminf(fmaxf(v.x * sx, -FP8_MAX_F), FP8_MAX_F);
        float a1 = fminf(fmaxf(v.y * sx, -FP8_MAX_F), FP8_MAX_F);
        float a2 = fminf(fmaxf(v.z * sx, -FP8_MAX_F), FP8_MAX_F);
        float a3 = fminf(fmaxf(v.w * sx, -FP8_MAX_F), FP8_MAX_F);
        int p = __builtin_amdgcn_cvt_pk_fp8_f32(a0, a1, 0, false);
        p = __builtin_amdgcn_cvt_pk_fp8_f32(a2, a3, p, true);
        xq[j] = (unsigned int)p;
    }
    #pragma unroll 2
    for (long j = tid; j < wn4; j += stride) {
        float4 v = wv[j];
        float a0 = fminf(fmaxf(v.x * sw, -FP8_MAX_F), FP8_MAX_F);
        float a1 = fminf(fmaxf(v.y * sw, -FP8_MAX_F), FP8_MAX_F);
        float a2 = fminf(fmaxf(v.z * sw, -FP8_MAX_F), FP8_MAX_F);
        float a3 = fminf(fmaxf(v.w * sw, -FP8_MAX_F), FP8_MAX_F);
        int p = __builtin_amdgcn_cvt_pk_fp8_f32(a0, a1, 0, false);
        p = __builtin_amdgcn_cvt_pk_fp8_f32(a2, a3, p, true);
        wq[j] = (unsigned int)p;
    }
}

// --- GEMM: C[m,n] = sum_k A8[m,k]*W8[n,k]; epilogue C = acc*rcp + bias[n]
// 128x128 tile, BK=128 bytes, 4 waves x 4x4 tiles of 16x16x128 scaled-fp8 MFMA.
// LDS layout XOR-swizzled at 16B granularity: LDS[r][b] = G[r][b ^ (r&7)].
#define BM 128
#define BN 128
#define BKB 128

__global__ __launch_bounds__(256, 3) void gemm_fp8mx(
    const unsigned char* __restrict__ A,  // [M,K] fp8
    const unsigned char* __restrict__ B,  // [N,K] fp8
    const float* __restrict__ bias,       // [N]
    const unsigned int* __restrict__ amax,
    float* __restrict__ C,                // [M,N] fp32
    int M, int N, int K) {
    __shared__ __align__(16) unsigned char As[BM * BKB];  // 16 KB
    __shared__ __align__(16) unsigned char Bs[BN * BKB];  // 16 KB

    const int t = threadIdx.x;
    const int lane = t & 63;
    const int w = t >> 6;

    // XCD-aware bijective swizzle: XCD k (flat%8==k) computes 256 consecutive
    // tiles = 16 full A-panel rows x all 16 B columns -> B L2-resident per XCD.
    int flat = blockIdx.y * gridDim.x + blockIdx.x;
    const int nwg = gridDim.x * gridDim.y;
    if ((nwg & 7) == 0) flat = (flat & 7) * (nwg >> 3) + (flat >> 3);
    const int bm = (flat / gridDim.x) * BM;
    const int bn = (flat % gridDim.x) * BN;

    const int wm = (w >> 1) * 64;
    const int wn = (w & 1) * 64;

    floatx4 acc[4][4] = {};

    // staging: thread t -> LDS linear slot t*16 == (row = t>>3, blk = t&7);
    // load the XOR-swizzled global 16B block so LDS[r][b] = G[r][b^(r&7)]
    const int srow = t >> 3;                       // 0..31
    const int gcol = ((t & 7) ^ (srow & 7)) * 16;  // swizzled 16B block
    const unsigned char* gA = A + (long)(bm + srow) * K + gcol;
    const unsigned char* gB = B + (long)(bn + srow) * K + gcol;
    unsigned char* lA = As + t * 16;
    unsigned char* lB = Bs + t * 16;

    // fragment addressing: 16x16x128 f8f6f4 A/B: lane holds
    // elem (l&15, (l>>4)*32 + j), j=0..31 -> two swizzled 16B reads
    const int fr = lane & 15;
    const int sw = fr & 7;
    const int b0 = (lane >> 4) * 2;
    const int off0 = (b0 ^ sw) * 16;
    const int off1 = ((b0 + 1) ^ sw) * 16;
    const int rowA = (wm + fr) * BKB;
    const int rowB = (wn + fr) * BKB;

    for (int kt = 0; kt < K; kt += BKB) {
        __syncthreads();
        #pragma unroll
        for (int c = 0; c < 4; c++) {
            async_load16(gA + (long)c * 32 * K + kt, lA + c * 4096);
            async_load16(gB + (long)c * 32 * K + kt, lB + c * 4096);
        }
        __syncthreads();

        intx8 bfrag[4];
        #pragma unroll
        for (int j = 0; j < 4; j++) {
            intx4 lo = *(const intx4*)(Bs + rowB + j * 2048 + off0);
            intx4 hi = *(const intx4*)(Bs + rowB + j * 2048 + off1);
            bfrag[j] = (intx8){lo.x, lo.y, lo.z, lo.w, hi.x, hi.y, hi.z, hi.w};
        }
        #pragma unroll
        for (int i = 0; i < 4; i++) {
            intx4 lo = *(const intx4*)(As + rowA + i * 2048 + off0);
            intx4 hi = *(const intx4*)(As + rowA + i * 2048 + off1);
            intx8 afrag = (intx8){lo.x, lo.y, lo.z, lo.w, hi.x, hi.y, hi.z, hi.w};
            #pragma unroll
            for (int j = 0; j < 4; j++)
                acc[i][j] = __builtin_amdgcn_mfma_scale_f32_16x16x128_f8f6f4(
                    afrag, bfrag[j], acc[i][j],
                    /*cbsz=fp8*/ 0, /*blgp=fp8*/ 0,
                    0, 0x7f7f7f7f, 0, 0x7f7f7f7f);  // unit e8m0 scales
        }
    }

    // epilogue: C/D layout col = lane&15, row = (lane>>4)*4 + reg (16x16 shapes)
    const float is = scale_from_amax(amax[0]);
    const float ws = scale_from_amax(amax[1]);
    const float rcp = 1.0f / (is * ws);
    const int crow = bm + wm + (lane >> 4) * 4;
    const int ccol = bn + wn + fr;
    #pragma unroll
    for (int j = 0; j < 4; j++) {
        const int col = ccol + j * 16;
        const float bv = bias[col];
        #pragma unroll
        for (int i = 0; i < 4; i++) {
            const int row0 = crow + i * 16;
            #pragma unroll
            for (int r = 0; r < 4; r++)
                C[(long)(row0 + r) * N + col] = acc[i][j][r] * rcp + bv;
        }
    }
}

extern "C" void kernel_launch(void* const* d_in, const int* in_sizes, int n_in,
                              void* d_out, int out_size, void* d_ws, size_t ws_size,
                              hipStream_t stream) {
    const float* x = (const float*)d_in[0];    // [B,S,K] fp32
    const float* wt = (const float*)d_in[1];   // [N,K] fp32
    const float* bias = (const float*)d_in[2]; // [N] fp32
    float* out = (float*)d_out;                // [B*S, N] fp32

    const int xn = in_sizes[0];  // M*K
    const int wn = in_sizes[1];  // N*K
    const int N = in_sizes[2];
    const int K = wn / N;
    const int M = xn / K;

    unsigned char* wsb = (unsigned char*)d_ws;
    unsigned int* amax = (unsigned int*)wsb;            // 2 u32
    float* partials = (float*)(wsb + 64);               // 2*SGRID floats
    unsigned char* xq = wsb + 64 + 2 * SGRID * 4;       // M*K bytes
    unsigned char* wq = xq + (size_t)xn;                // N*K bytes

    long xn4 = (long)xn / 4, wn4 = (long)wn / 4;
    amax_partial<<<SGRID, 256, 0, stream>>>(x, xn4, wt, wn4, partials);
    quant_both<<<SGRID, 256, 0, stream>>>(x, xn4, wt, wn4, partials, amax,
                                          (unsigned int*)xq, (unsigned int*)wq);
    dim3 grid(N / BN, M / BM);
    gemm_fp8mx<<<grid, 256, 0, stream>>>(xq, wq, bias, amax, out, M, N, K);
}

// Round 3
// 345.384 us; speedup vs baseline: 1.2451x; 1.0316x over previous
//
#include <hip/hip_runtime.h>

// ---------------------------------------------------------------------------
// FP8Linear: out = (q8(x*sx) @ q8(W*sw)^T) / (sx*sw) + bias
// M=16384, K=2048, N=2048
// R5: side kernels rewritten for ILP — R1 evidence (VGPR_Count=16, 1.1 TB/s,
// VALUBusy 5%) says the compiler kept only ~2 loads in flight -> latency-bound.
// Hand-batched independent float4 loads (8-deep cold / 4-deep LLC-warm) force
// 8 global_load_dwordx4 in flight per wave at <=64 VGPR (full occupancy).
// GEMM: XCD swizzle kept; NT stores on C re-added (confound-free this time:
// gemm counters visible in top-5; C is write-once, protect L2-resident B).
// ---------------------------------------------------------------------------

typedef __attribute__((ext_vector_type(4))) float floatx4;
typedef __attribute__((ext_vector_type(4))) int intx4;
typedef __attribute__((ext_vector_type(8))) int intx8;

#define FP8_MAX_F 448.0f
#define SGRID 2048

__device__ __forceinline__ void async_load16(const void* g, void* l) {
    __builtin_amdgcn_global_load_lds(
        (const __attribute__((address_space(1))) unsigned int*)g,
        (__attribute__((address_space(3))) unsigned int*)l,
        16, 0, 0);
}

__device__ __forceinline__ float scale_from_amax_f(float a) {
    // must be the exact fp32 op sequence everywhere it is recomputed
    return FP8_MAX_F / (a + 1e-12f) * 0.9f;
}
__device__ __forceinline__ float scale_from_amax(unsigned int bits) {
    return scale_from_amax_f(__uint_as_float(bits));
}

__device__ __forceinline__ float amax4(float4 v) {
    return fmaxf(fmaxf(fabsf(v.x), fabsf(v.y)), fmaxf(fabsf(v.z), fabsf(v.w)));
}

// --- pass 1: per-block partial amax over x and w. 8-deep batched loads.
__global__ __launch_bounds__(256) void amax_partial(
    const float* __restrict__ x, long xn4,
    const float* __restrict__ w, long wn4,
    float* __restrict__ partials) {  // [2][SGRID] in ws
    const float4* xv = (const float4*)x;
    const float4* wv = (const float4*)w;
    const long tid = (long)blockIdx.x * 256 + threadIdx.x;
    const long st = (long)SGRID * 256;

    float mx = 0.0f, mw = 0.0f;
    long j = tid;
    // 8 independent named loads -> 8 dwordx4 in flight per wave
    for (; j + 7 * st < xn4; j += 8 * st) {
        float4 a0 = xv[j];
        float4 a1 = xv[j + st];
        float4 a2 = xv[j + 2 * st];
        float4 a3 = xv[j + 3 * st];
        float4 a4 = xv[j + 4 * st];
        float4 a5 = xv[j + 5 * st];
        float4 a6 = xv[j + 6 * st];
        float4 a7 = xv[j + 7 * st];
        float m01 = fmaxf(amax4(a0), amax4(a1));
        float m23 = fmaxf(amax4(a2), amax4(a3));
        float m45 = fmaxf(amax4(a4), amax4(a5));
        float m67 = fmaxf(amax4(a6), amax4(a7));
        mx = fmaxf(mx, fmaxf(fmaxf(m01, m23), fmaxf(m45, m67)));
    }
    for (; j < xn4; j += st) mx = fmaxf(mx, amax4(xv[j]));

    j = tid;
    for (; j + st < wn4; j += 2 * st) {
        float4 b0 = wv[j];
        float4 b1 = wv[j + st];
        mw = fmaxf(mw, fmaxf(amax4(b0), amax4(b1)));
    }
    for (; j < wn4; j += st) mw = fmaxf(mw, amax4(wv[j]));

    #pragma unroll
    for (int off = 32; off > 0; off >>= 1) {
        mx = fmaxf(mx, __shfl_down(mx, off));
        mw = fmaxf(mw, __shfl_down(mw, off));
    }
    __shared__ float red[2][4];
    const int lane = threadIdx.x & 63, wid = threadIdx.x >> 6;
    if (lane == 0) { red[0][wid] = mx; red[1][wid] = mw; }
    __syncthreads();
    if (threadIdx.x == 0) {
        partials[blockIdx.x] =
            fmaxf(fmaxf(red[0][0], red[0][1]), fmaxf(red[0][2], red[0][3]));
        partials[SGRID + blockIdx.x] =
            fmaxf(fmaxf(red[1][0], red[1][1]), fmaxf(red[1][2], red[1][3]));
    }
}

// --- pass 2: redundant partials reduce (every block, deterministic) ->
// write amax bits (block 0) -> quantize x and w. x/w re-reads are LLC-warm,
// 4-deep batching suffices.
__global__ __launch_bounds__(256) void quant_both(
    const float* __restrict__ x, long xn4,
    const float* __restrict__ w, long wn4,
    const float* __restrict__ partials,
    unsigned int* __restrict__ amax,    // 2 u32 for gemm epilogue
    unsigned int* __restrict__ xq,
    unsigned int* __restrict__ wq) {
    float mx = 0.0f, mw = 0.0f;
    for (int p = threadIdx.x; p < SGRID; p += 256) {
        mx = fmaxf(mx, partials[p]);
        mw = fmaxf(mw, partials[SGRID + p]);
    }
    #pragma unroll
    for (int off = 32; off > 0; off >>= 1) {
        mx = fmaxf(mx, __shfl_down(mx, off));
        mw = fmaxf(mw, __shfl_down(mw, off));
    }
    __shared__ float red[2][4];
    const int lane = threadIdx.x & 63, wid = threadIdx.x >> 6;
    if (lane == 0) { red[0][wid] = mx; red[1][wid] = mw; }
    __syncthreads();
    mx = fmaxf(fmaxf(red[0][0], red[0][1]), fmaxf(red[0][2], red[0][3]));
    mw = fmaxf(fmaxf(red[1][0], red[1][1]), fmaxf(red[1][2], red[1][3]));
    if (blockIdx.x == 0 && threadIdx.x == 0) {
        amax[0] = __float_as_uint(mx);
        amax[1] = __float_as_uint(mw);
    }

    const float sx = scale_from_amax_f(mx);
    const float sw = scale_from_amax_f(mw);
    const float4* xv = (const float4*)x;
    const float4* wv = (const float4*)w;
    const long tid = (long)blockIdx.x * 256 + threadIdx.x;
    const long st = (long)SGRID * 256;

    long j = tid;
    for (; j + 3 * st < xn4; j += 4 * st) {
        float4 v0 = xv[j];
        float4 v1 = xv[j + st];
        float4 v2 = xv[j + 2 * st];
        float4 v3 = xv[j + 3 * st];
        unsigned int q[4];
        float4 vv[4] = {v0, v1, v2, v3};
        #pragma unroll
        for (int u = 0; u < 4; u++) {
            float a0 = fminf(fmaxf(vv[u].x * sx, -FP8_MAX_F), FP8_MAX_F);
            float a1 = fminf(fmaxf(vv[u].y * sx, -FP8_MAX_F), FP8_MAX_F);
            float a2 = fminf(fmaxf(vv[u].z * sx, -FP8_MAX_F), FP8_MAX_F);
            float a3 = fminf(fmaxf(vv[u].w * sx, -FP8_MAX_F), FP8_MAX_F);
            int p = __builtin_amdgcn_cvt_pk_fp8_f32(a0, a1, 0, false);
            p = __builtin_amdgcn_cvt_pk_fp8_f32(a2, a3, p, true);
            q[u] = (unsigned int)p;
        }
        xq[j] = q[0];
        xq[j + st] = q[1];
        xq[j + 2 * st] = q[2];
        xq[j + 3 * st] = q[3];
    }
    for (; j < xn4; j += st) {
        float4 v = xv[j];
        float a0 = fminf(fmaxf(v.x * sx, -FP8_MAX_F), FP8_MAX_F);
        float a1 = fminf(fmaxf(v.y * sx, -FP8_MAX_F), FP8_MAX_F);
        float a2 = fminf(fmaxf(v.z * sx, -FP8_MAX_F), FP8_MAX_F);
        float a3 = fminf(fmaxf(v.w * sx, -FP8_MAX_F), FP8_MAX_F);
        int p = __builtin_amdgcn_cvt_pk_fp8_f32(a0, a1, 0, false);
        p = __builtin_amdgcn_cvt_pk_fp8_f32(a2, a3, p, true);
        xq[j] = (unsigned int)p;
    }

    j = tid;
    for (; j + st < wn4; j += 2 * st) {
        float4 v0 = wv[j];
        float4 v1 = wv[j + st];
        unsigned int q[2];
        float4 vv[2] = {v0, v1};
        #pragma unroll
        for (int u = 0; u < 2; u++) {
            float a0 = fminf(fmaxf(vv[u].x * sw, -FP8_MAX_F), FP8_MAX_F);
            float a1 = fminf(fmaxf(vv[u].y * sw, -FP8_MAX_F), FP8_MAX_F);
            float a2 = fminf(fmaxf(vv[u].z * sw, -FP8_MAX_F), FP8_MAX_F);
            float a3 = fminf(fmaxf(vv[u].w * sw, -FP8_MAX_F), FP8_MAX_F);
            int p = __builtin_amdgcn_cvt_pk_fp8_f32(a0, a1, 0, false);
            p = __builtin_amdgcn_cvt_pk_fp8_f32(a2, a3, p, true);
            q[u] = (unsigned int)p;
        }
        wq[j] = q[0];
        wq[j + st] = q[1];
    }
    for (; j < wn4; j += st) {
        float4 v = wv[j];
        float a0 = fminf(fmaxf(v.x * sw, -FP8_MAX_F), FP8_MAX_F);
        float a1 = fminf(fmaxf(v.y * sw, -FP8_MAX_F), FP8_MAX_F);
        float a2 = fminf(fmaxf(v.z * sw, -FP8_MAX_F), FP8_MAX_F);
        float a3 = fminf(fmaxf(v.w * sw, -FP8_MAX_F), FP8_MAX_F);
        int p = __builtin_amdgcn_cvt_pk_fp8_f32(a0, a1, 0, false);
        p = __builtin_amdgcn_cvt_pk_fp8_f32(a2, a3, p, true);
        wq[j] = (unsigned int)p;
    }
}

// --- GEMM: C[m,n] = sum_k A8[m,k]*W8[n,k]; epilogue C = acc*rcp + bias[n]
// 128x128 tile, BK=128 bytes, 4 waves x 4x4 tiles of 16x16x128 scaled-fp8 MFMA.
// LDS layout XOR-swizzled at 16B granularity: LDS[r][b] = G[r][b ^ (r&7)].
#define BM 128
#define BN 128
#define BKB 128

__global__ __launch_bounds__(256, 3) void gemm_fp8mx(
    const unsigned char* __restrict__ A,  // [M,K] fp8
    const unsigned char* __restrict__ B,  // [N,K] fp8
    const float* __restrict__ bias,       // [N]
    const unsigned int* __restrict__ amax,
    float* __restrict__ C,                // [M,N] fp32
    int M, int N, int K) {
    __shared__ __align__(16) unsigned char As[BM * BKB];  // 16 KB
    __shared__ __align__(16) unsigned char Bs[BN * BKB];  // 16 KB

    const int t = threadIdx.x;
    const int lane = t & 63;
    const int w = t >> 6;

    // XCD-aware bijective swizzle: XCD k (flat%8==k) computes 256 consecutive
    // tiles = 16 full A-panel rows x all 16 B columns -> B L2-resident per XCD.
    int flat = blockIdx.y * gridDim.x + blockIdx.x;
    const int nwg = gridDim.x * gridDim.y;
    if ((nwg & 7) == 0) flat = (flat & 7) * (nwg >> 3) + (flat >> 3);
    const int bm = (flat / gridDim.x) * BM;
    const int bn = (flat % gridDim.x) * BN;

    const int wm = (w >> 1) * 64;
    const int wn = (w & 1) * 64;

    floatx4 acc[4][4] = {};

    // staging: thread t -> LDS linear slot t*16 == (row = t>>3, blk = t&7);
    // load the XOR-swizzled global 16B block so LDS[r][b] = G[r][b^(r&7)]
    const int srow = t >> 3;                       // 0..31
    const int gcol = ((t & 7) ^ (srow & 7)) * 16;  // swizzled 16B block
    const unsigned char* gA = A + (long)(bm + srow) * K + gcol;
    const unsigned char* gB = B + (long)(bn + srow) * K + gcol;
    unsigned char* lA = As + t * 16;
    unsigned char* lB = Bs + t * 16;

    // fragment addressing: 16x16x128 f8f6f4 A/B: lane holds
    // elem (l&15, (l>>4)*32 + j), j=0..31 -> two swizzled 16B reads
    const int fr = lane & 15;
    const int sw = fr & 7;
    const int b0 = (lane >> 4) * 2;
    const int off0 = (b0 ^ sw) * 16;
    const int off1 = ((b0 + 1) ^ sw) * 16;
    const int rowA = (wm + fr) * BKB;
    const int rowB = (wn + fr) * BKB;

    for (int kt = 0; kt < K; kt += BKB) {
        __syncthreads();
        #pragma unroll
        for (int c = 0; c < 4; c++) {
            async_load16(gA + (long)c * 32 * K + kt, lA + c * 4096);
            async_load16(gB + (long)c * 32 * K + kt, lB + c * 4096);
        }
        __syncthreads();

        intx8 bfrag[4];
        #pragma unroll
        for (int j = 0; j < 4; j++) {
            intx4 lo = *(const intx4*)(Bs + rowB + j * 2048 + off0);
            intx4 hi = *(const intx4*)(Bs + rowB + j * 2048 + off1);
            bfrag[j] = (intx8){lo.x, lo.y, lo.z, lo.w, hi.x, hi.y, hi.z, hi.w};
        }
        #pragma unroll
        for (int i = 0; i < 4; i++) {
            intx4 lo = *(const intx4*)(As + rowA + i * 2048 + off0);
            intx4 hi = *(const intx4*)(As + rowA + i * 2048 + off1);
            intx8 afrag = (intx8){lo.x, lo.y, lo.z, lo.w, hi.x, hi.y, hi.z, hi.w};
            #pragma unroll
            for (int j = 0; j < 4; j++)
                acc[i][j] = __builtin_amdgcn_mfma_scale_f32_16x16x128_f8f6f4(
                    afrag, bfrag[j], acc[i][j],
                    /*cbsz=fp8*/ 0, /*blgp=fp8*/ 0,
                    0, 0x7f7f7f7f, 0, 0x7f7f7f7f);  // unit e8m0 scales
        }
    }

    // epilogue: C/D layout col = lane&15, row = (lane>>4)*4 + reg (16x16 shapes)
    const float is = scale_from_amax(amax[0]);
    const float ws = scale_from_amax(amax[1]);
    const float rcp = 1.0f / (is * ws);
    const int crow = bm + wm + (lane >> 4) * 4;
    const int ccol = bn + wn + fr;
    #pragma unroll
    for (int j = 0; j < 4; j++) {
        const int col = ccol + j * 16;
        const float bv = bias[col];
        #pragma unroll
        for (int i = 0; i < 4; i++) {
            const int row0 = crow + i * 16;
            #pragma unroll
            for (int r = 0; r < 4; r++)
                __builtin_nontemporal_store(acc[i][j][r] * rcp + bv,
                                            &C[(long)(row0 + r) * N + col]);
        }
    }
}

extern "C" void kernel_launch(void* const* d_in, const int* in_sizes, int n_in,
                              void* d_out, int out_size, void* d_ws, size_t ws_size,
                              hipStream_t stream) {
    const float* x = (const float*)d_in[0];    // [B,S,K] fp32
    const float* wt = (const float*)d_in[1];   // [N,K] fp32
    const float* bias = (const float*)d_in[2]; // [N] fp32
    float* out = (float*)d_out;                // [B*S, N] fp32

    const int xn = in_sizes[0];  // M*K
    const int wn = in_sizes[1];  // N*K
    const int N = in_sizes[2];
    const int K = wn / N;
    const int M = xn / K;

    unsigned char* wsb = (unsigned char*)d_ws;
    unsigned int* amax = (unsigned int*)wsb;            // 2 u32
    float* partials = (float*)(wsb + 64);               // 2*SGRID floats
    unsigned char* xq = wsb + 64 + 2 * SGRID * 4;       // M*K bytes
    unsigned char* wq = xq + (size_t)xn;                // N*K bytes

    long xn4 = (long)xn / 4, wn4 = (long)wn / 4;
    amax_partial<<<SGRID, 256, 0, stream>>>(x, xn4, wt, wn4, partials);
    quant_both<<<SGRID, 256, 0, stream>>>(x, xn4, wt, wn4, partials, amax,
                                          (unsigned int*)xq, (unsigned int*)wq);
    dim3 grid(N / BN, M / BM);
    gemm_fp8mx<<<grid, 256, 0, stream>>>(xq, wq, bias, amax, out, M, N, K);
}